// Round 1
// baseline (526.535 us; speedup 1.0000x reference)
//
#include <hip/hip_runtime.h>
#include <hip/hip_bf16.h>
#include <math.h>

#define NF 256
#define NH 64
#define NC 16

// ---------------- degree count ----------------
__global__ void k_count(const int* __restrict__ dst, int* __restrict__ cnt, int E) {
    int i = blockIdx.x * 256 + threadIdx.x;
    if (i < E) atomicAdd(&cnt[dst[i]], 1);
}

// dinv[v] = rsqrt(indeg + 1)  (self-loop included in degree)
__global__ void k_dinv(const int* __restrict__ cnt, float* __restrict__ dinv, int n) {
    int i = blockIdx.x * 256 + threadIdx.x;
    if (i < n) dinv[i] = rsqrtf((float)(cnt[i] + 1));
}

// ---------------- exclusive scan (3 kernels) ----------------
__global__ void k_scan1(const int* __restrict__ cnt, int* __restrict__ rowptr,
                        int* __restrict__ bsums, int n) {
    __shared__ int s[256];
    int t = threadIdx.x;
    int i = blockIdx.x * 256 + t;
    int v = (i < n) ? cnt[i] : 0;
    s[t] = v;
    __syncthreads();
    for (int off = 1; off < 256; off <<= 1) {
        int add = (t >= off) ? s[t - off] : 0;
        __syncthreads();
        s[t] += add;
        __syncthreads();
    }
    if (i < n) rowptr[i] = s[t] - v;           // block-local exclusive
    if (t == 255) bsums[blockIdx.x] = s[255];  // block total
}

__global__ void k_scan2(int* __restrict__ bsums, int nb) {
    __shared__ int s[512];
    int t = threadIdx.x;
    int v = (t < nb) ? bsums[t] : 0;
    s[t] = v;
    __syncthreads();
    for (int off = 1; off < 512; off <<= 1) {
        int add = (t >= off) ? s[t - off] : 0;
        __syncthreads();
        s[t] += add;
        __syncthreads();
    }
    if (t < nb) bsums[t] = s[t] - v;  // exclusive scan of block sums
}

__global__ void k_scan3(int* __restrict__ rowptr, const int* __restrict__ bsums,
                        int* __restrict__ cursor, int n) {
    int i = blockIdx.x * 256 + threadIdx.x;
    if (i < n) {
        int r = rowptr[i] + bsums[blockIdx.x];
        rowptr[i] = r;
        cursor[i] = r;
    }
}

// ---------------- CSR fill ----------------
__global__ void k_fill(const int* __restrict__ src, const int* __restrict__ dst,
                       int* __restrict__ cursor, int* __restrict__ esrc, int E) {
    int i = blockIdx.x * 256 + threadIdx.x;
    if (i < E) {
        int d = dst[i];
        int p = atomicAdd(&cursor[d], 1);
        esrc[p] = src[i];
    }
}

// ---------------- GEMM1: h1 = x @ W1   [n,256]x[256,64] ----------------
// 64x64 tile, BK=16, 256 threads, each thread computes 4x4.
__global__ void k_gemm1(const float* __restrict__ x, const float* __restrict__ W1,
                        float* __restrict__ h1, int n) {
    __shared__ float As[16][64];  // x tile transposed: [k][m]
    __shared__ float Bs[16][64];  // W1 tile: [k][col]
    int tid = threadIdx.x;
    int tx = tid & 15;   // col group
    int ty = tid >> 4;   // row group
    int m0 = blockIdx.x * 64;
    float acc[4][4] = {{0.f}};

    for (int k0 = 0; k0 < NF; k0 += 16) {
        // stage x: thread loads one float4: row = tid/4, k-chunk = tid%4
        {
            int lm = tid >> 2;
            int lk4 = (tid & 3) * 4;
            int node = m0 + lm;
            float4 xv = make_float4(0.f, 0.f, 0.f, 0.f);
            if (node < n) xv = *(const float4*)&x[(size_t)node * NF + k0 + lk4];
            As[lk4 + 0][lm] = xv.x;
            As[lk4 + 1][lm] = xv.y;
            As[lk4 + 2][lm] = xv.z;
            As[lk4 + 3][lm] = xv.w;
        }
        // stage W1: 16x64 = 1024 elems, 4 per thread, coalesced
        #pragma unroll
        for (int r = 0; r < 4; ++r) {
            int idx = tid + r * 256;
            int kk = idx >> 6;
            int col = idx & 63;
            Bs[kk][col] = W1[(size_t)(k0 + kk) * NH + col];
        }
        __syncthreads();
        #pragma unroll
        for (int kk = 0; kk < 16; ++kk) {
            float4 a = *(const float4*)&As[kk][4 * ty];
            float4 b = *(const float4*)&Bs[kk][4 * tx];
            float av[4] = {a.x, a.y, a.z, a.w};
            float bv[4] = {b.x, b.y, b.z, b.w};
            #pragma unroll
            for (int i = 0; i < 4; ++i)
                #pragma unroll
                for (int j = 0; j < 4; ++j)
                    acc[i][j] = fmaf(av[i], bv[j], acc[i][j]);
        }
        __syncthreads();
    }
    #pragma unroll
    for (int i = 0; i < 4; ++i) {
        int node = m0 + 4 * ty + i;
        if (node < n) {
            float4 o = make_float4(acc[i][0], acc[i][1], acc[i][2], acc[i][3]);
            *(float4*)&h1[(size_t)node * NH + 4 * tx] = o;
        }
    }
}

// ---------------- agg1: h1agg = relu( D^-1/2 (A+I) D^-1/2 h1 + b1 ) ------------
// wave per node, lane per feature (64)
__global__ void k_agg1(const float* __restrict__ h1, const float* __restrict__ dinv,
                       const int* __restrict__ rowptr, const int* __restrict__ cnt,
                       const int* __restrict__ esrc, const float* __restrict__ b1,
                       float* __restrict__ h1agg, int n) {
    int wave = threadIdx.x >> 6;
    int lane = threadIdx.x & 63;
    int v = blockIdx.x * 4 + wave;
    if (v >= n) return;
    float dv = dinv[v];
    float acc = dv * dv * h1[(size_t)v * NH + lane];
    int beg = rowptr[v];
    int end = beg + cnt[v];
    int e = beg;
    for (; e + 1 < end; e += 2) {
        int s0 = esrc[e];
        int s1 = esrc[e + 1];
        float w0 = dinv[s0] * dv;
        float w1 = dinv[s1] * dv;
        float v0 = h1[(size_t)s0 * NH + lane];
        float v1 = h1[(size_t)s1 * NH + lane];
        acc = fmaf(w0, v0, acc);
        acc = fmaf(w1, v1, acc);
    }
    if (e < end) {
        int s0 = esrc[e];
        acc = fmaf(dinv[s0] * dv, h1[(size_t)s0 * NH + lane], acc);
    }
    acc += b1[lane];
    h1agg[(size_t)v * NH + lane] = fmaxf(acc, 0.f);
}

// ---------------- GEMM2: g = h1agg @ W2   [n,64]x[64,16] ----------------
__global__ void k_gemm2(const float* __restrict__ h1agg, const float* __restrict__ W2,
                        float* __restrict__ g, int n) {
    __shared__ float W2s[NH * NC];
    {
        int t = threadIdx.x;
        #pragma unroll
        for (int r = 0; r < 4; ++r) W2s[t + r * 256] = W2[t + r * 256];
    }
    __syncthreads();
    int grp = threadIdx.x >> 4;
    int c = threadIdx.x & 15;
    int v = blockIdx.x * 16 + grp;
    if (v >= n) return;
    float acc = 0.f;
    const float* row = &h1agg[(size_t)v * NH];
    #pragma unroll
    for (int k4 = 0; k4 < NH; k4 += 4) {
        float4 h = *(const float4*)&row[k4];
        acc = fmaf(h.x, W2s[(k4 + 0) * NC + c], acc);
        acc = fmaf(h.y, W2s[(k4 + 1) * NC + c], acc);
        acc = fmaf(h.z, W2s[(k4 + 2) * NC + c], acc);
        acc = fmaf(h.w, W2s[(k4 + 3) * NC + c], acc);
    }
    g[(size_t)v * NC + c] = acc;
}

// ---------------- agg2 + bias + log_softmax ----------------
// 16 lanes per node
__global__ void k_agg2(const float* __restrict__ g, const float* __restrict__ dinv,
                       const int* __restrict__ rowptr, const int* __restrict__ cnt,
                       const int* __restrict__ esrc, const float* __restrict__ b2,
                       float* __restrict__ out, int n) {
    int grp = threadIdx.x >> 4;
    int lane = threadIdx.x & 15;
    int v = blockIdx.x * 16 + grp;
    if (v >= n) return;
    float dv = dinv[v];
    float acc = dv * dv * g[(size_t)v * NC + lane];
    int beg = rowptr[v];
    int end = beg + cnt[v];
    int e = beg;
    for (; e + 1 < end; e += 2) {
        int s0 = esrc[e];
        int s1 = esrc[e + 1];
        float w0 = dinv[s0] * dv;
        float w1 = dinv[s1] * dv;
        float v0 = g[(size_t)s0 * NC + lane];
        float v1 = g[(size_t)s1 * NC + lane];
        acc = fmaf(w0, v0, acc);
        acc = fmaf(w1, v1, acc);
    }
    if (e < end) {
        int s0 = esrc[e];
        acc = fmaf(dinv[s0] * dv, g[(size_t)s0 * NC + lane], acc);
    }
    acc += b2[lane];
    // log_softmax over 16 lanes
    float m = acc;
    #pragma unroll
    for (int mask = 1; mask < 16; mask <<= 1)
        m = fmaxf(m, __shfl_xor(m, mask, 16));
    float ex = __expf(acc - m);
    float ssum = ex;
    #pragma unroll
    for (int mask = 1; mask < 16; mask <<= 1)
        ssum += __shfl_xor(ssum, mask, 16);
    out[(size_t)v * NC + lane] = acc - m - __logf(ssum);
}

extern "C" void kernel_launch(void* const* d_in, const int* in_sizes, int n_in,
                              void* d_out, int out_size, void* d_ws, size_t ws_size,
                              hipStream_t stream) {
    const float* x  = (const float*)d_in[0];
    const int*   ei = (const int*)d_in[1];
    const float* W1 = (const float*)d_in[2];
    const float* b1 = (const float*)d_in[3];
    const float* W2 = (const float*)d_in[4];
    const float* b2 = (const float*)d_in[5];
    float* out = (float*)d_out;

    const int N = in_sizes[0] / NF;
    const int E = in_sizes[1] / 2;
    const int* src = ei;
    const int* dst = ei + E;

    // workspace layout
    char* ws = (char*)d_ws;
    size_t o = 0;
    int*   cnt    = (int*)(ws + o);   o += 512 * 1024;
    float* dinv   = (float*)(ws + o); o += 512 * 1024;
    int*   rowptr = (int*)(ws + o);   o += 512 * 1024;
    int*   cursor = (int*)(ws + o);   o += 512 * 1024;
    int*   bsums  = (int*)(ws + o);   o += 4 * 1024;
    int*   esrc   = (int*)(ws + o);   o += (size_t)E * 4 + 1024;
    float* h1     = (float*)(ws + o); o += (size_t)N * NH * 4;
    float* h1agg  = (float*)(ws + o); o += (size_t)N * NH * 4;
    float* g      = h1;  // alias: h1 dead after agg1

    hipMemsetAsync(cnt, 0, (size_t)N * 4, stream);

    int gE = (E + 255) / 256;
    int gN = (N + 255) / 256;
    int nb1 = (N + 255) / 256;  // scan blocks (<=512)

    k_count<<<gE, 256, 0, stream>>>(dst, cnt, E);
    k_dinv<<<gN, 256, 0, stream>>>(cnt, dinv, N);
    k_scan1<<<nb1, 256, 0, stream>>>(cnt, rowptr, bsums, N);
    k_scan2<<<1, 512, 0, stream>>>(bsums, nb1);
    k_scan3<<<nb1, 256, 0, stream>>>(rowptr, bsums, cursor, N);
    k_fill<<<gE, 256, 0, stream>>>(src, dst, cursor, esrc, E);

    k_gemm1<<<(N + 63) / 64, 256, 0, stream>>>(x, W1, h1, N);
    k_agg1<<<(N + 3) / 4, 256, 0, stream>>>(h1, dinv, rowptr, cnt, esrc, b1, h1agg, N);
    k_gemm2<<<(N + 15) / 16, 256, 0, stream>>>(h1agg, W2, g, N);
    k_agg2<<<(N + 15) / 16, 256, 0, stream>>>(g, dinv, rowptr, cnt, esrc, b2, out, N);
}